// Round 5
// baseline (38003.516 us; speedup 1.0000x reference)
//
#include <hip/hip_runtime.h>
#include <math.h>

// Problem constants (match reference)
constexpr int NN  = 100000;   // nodes
constexpr int NE  = 1600000;  // edges
constexpr int NG  = 64;       // graphs
constexpr int HID = 128;
constexpr int OUT = 64;
// ACTS = [True, True, False, True, True, True]
static const bool hActs[6] = {true, true, false, true, true, true};

// ---------------- degree / norm precompute ----------------
__global__ void k_deg_init(float* deg) {
    int i = blockIdx.x * 256 + threadIdx.x;
    if (i < NN) deg[i] = 1.0f;  // self-loop weight
}

__global__ void k_deg_acc(const int* __restrict__ dst, const float* __restrict__ ew,
                          float* deg) {
    int e = blockIdx.x * 256 + threadIdx.x;
    if (e < NE) atomicAdd(&deg[dst[e]], ew[e]);
}

__global__ void k_dinv(float* deg) {
    int i = blockIdx.x * 256 + threadIdx.x;
    if (i < NN) {
        float d = deg[i];
        deg[i] = (d > 0.f) ? (1.0f / sqrtf(d)) : 0.0f;  // deg >= 1 always, but match ref
    }
}

__global__ void k_enorm(const int* __restrict__ src, const int* __restrict__ dst,
                        const float* __restrict__ ew, const float* __restrict__ dinv,
                        float* __restrict__ enorm) {
    int e = blockIdx.x * 256 + threadIdx.x;
    if (e < NE) enorm[e] = dinv[src[e]] * ew[e] * dinv[dst[e]];
}

// Graph start offsets via binary search (batch is sorted)
__global__ void k_bounds(const int* __restrict__ batch, int* __restrict__ start) {
    int g = threadIdx.x;  // 0..NG inclusive
    if (g > NG) return;
    int lo = 0, hi = NN;
    while (lo < hi) {
        int mid = (lo + hi) >> 1;
        if (batch[mid] < g) lo = mid + 1; else hi = mid;
    }
    start[g] = lo;
}

// ---------------- per-layer kernels ----------------
// xw[N,128] = x[N,128] @ W[128,128]; W staged in LDS (exactly 64KB).
// Fused epilogue: xc[n][c] = dinv[n]^2 * xw[n][c] + B[c]  (self-loop + bias)
__global__ __launch_bounds__(256) void k_matmul(const float* __restrict__ x,
                                                const float* __restrict__ W,
                                                const float* __restrict__ dinv,
                                                const float* __restrict__ B,
                                                float* __restrict__ xw,
                                                float* __restrict__ xc) {
    __shared__ float Ws[HID * HID];
    for (int i = threadIdx.x; i < HID * HID; i += 256) Ws[i] = W[i];
    __syncthreads();
    const int col  = threadIdx.x & 127;
    const int half = threadIdx.x >> 7;  // 0/1
    const float b = B[col];
    const int r0 = blockIdx.x * 64;
    const int rend = (r0 + 64 < NN) ? (r0 + 64) : NN;
    for (int r = r0 + half; r < rend; r += 2) {
        const float* xr = x + (size_t)r * HID;
        float acc = 0.f;
#pragma unroll
        for (int k = 0; k < HID; k += 4) {
            float4 xv = *(const float4*)(xr + k);  // broadcast across col-threads
            acc += xv.x * Ws[(k + 0) * HID + col];
            acc += xv.y * Ws[(k + 1) * HID + col];
            acc += xv.z * Ws[(k + 2) * HID + col];
            acc += xv.w * Ws[(k + 3) * HID + col];
        }
        xw[(size_t)r * HID + col] = acc;
        float d = dinv[r];
        xc[(size_t)r * HID + col] = d * d * acc + b;
    }
}

// atomics: out[dst] += enorm[e] * xw[src], 32 threads/edge x float4
__global__ void k_scatter(const int* __restrict__ src, const int* __restrict__ dst,
                          const float* __restrict__ enorm, const float* __restrict__ xw,
                          float* out) {
    int t = blockIdx.x * 256 + threadIdx.x;
    int e = t >> 5;
    if (e >= NE) return;
    int q = t & 31;
    int s = src[e], d = dst[e];
    float w = enorm[e];
    float4 v = *(const float4*)(xw + (size_t)s * HID + q * 4);
    float* o = out + (size_t)d * HID + q * 4;
    atomicAdd(o + 0, w * v.x);
    atomicAdd(o + 1, w * v.y);
    atomicAdd(o + 2, w * v.z);
    atomicAdd(o + 3, w * v.w);
}

__global__ void k_tanh(float* __restrict__ x) {
    int t = blockIdx.x * 256 + threadIdx.x;  // over NN*32 float4s
    if (t >= NN * 32) return;
    float4 v = ((float4*)x)[t];
    v.x = tanhf(v.x); v.y = tanhf(v.y); v.z = tanhf(v.z); v.w = tanhf(v.w);
    ((float4*)x)[t] = v;
}

// mean-pool per graph (applies tanh: last conv layer has act=True)
__global__ void k_pool(const float* __restrict__ x, const int* __restrict__ start,
                       float* __restrict__ h) {
    int g = blockIdx.x;
    int c = threadIdx.x;  // 128 threads
    int s = start[g], e = start[g + 1];
    float acc = 0.f;
#pragma unroll 4
    for (int n = s; n < e; ++n) acc += tanhf(x[(size_t)n * HID + c]);
    float cnt = (float)(e - s);
    h[g * HID + c] = acc / fmaxf(cnt, 1.0f);
}

// whole FC stack in one block
__global__ __launch_bounds__(256) void k_fc(const float* __restrict__ hpool,
                                            const float* __restrict__ fcW1,
                                            const float* __restrict__ fcb1,
                                            const float* __restrict__ fcW,
                                            const float* __restrict__ fcb,
                                            float* __restrict__ hout) {
    __shared__ float ha[NG * HID];  // 32KB; later reused as 64x64
    __shared__ float hb[NG * OUT];  // 16KB
    for (int i = threadIdx.x; i < NG * HID; i += 256) ha[i] = hpool[i];
    __syncthreads();
    // FC1: [64,128] @ [128,64] + b, relu
    for (int idx = threadIdx.x; idx < NG * OUT; idx += 256) {
        int g = idx >> 6, o = idx & 63;
        float acc = fcb1[o];
        for (int k = 0; k < HID; ++k) acc += ha[g * HID + k] * fcW1[k * OUT + o];
        hb[idx] = fmaxf(acc, 0.f);
    }
    __syncthreads();
    // 5 x [64,64] @ [64,64] + b, relu; ping-pong hb -> ha -> hb ...
    for (int l = 0; l < 5; ++l) {
        const float* in = (l & 1) ? ha : hb;
        float* outb     = (l & 1) ? hb : ha;
        const float* W = fcW + l * OUT * OUT;
        const float* b = fcb + l * OUT;
        for (int idx = threadIdx.x; idx < NG * OUT; idx += 256) {
            int g = idx >> 6, o = idx & 63;
            float acc = b[o];
            for (int k = 0; k < OUT; ++k) acc += in[g * OUT + k] * W[k * OUT + o];
            outb[idx] = fmaxf(acc, 0.f);
        }
        __syncthreads();
    }
    // after l=4 result is in ha
    for (int idx = threadIdx.x; idx < NG * OUT; idx += 256) hout[idx] = ha[idx];
}

__global__ void k_dist(const float* __restrict__ h1, const float* __restrict__ h2,
                       float* __restrict__ out) {
    int g = threadIdx.x;  // 64
    if (g >= NG) return;
    float acc = 0.f;
    for (int c = 0; c < OUT; ++c) {
        float d = h1[g * OUT + c] - h2[g * OUT + c];
        acc += d * d;
    }
    out[g] = sqrtf(acc);
}

// ---------------- host-side tower driver ----------------
static void run_tower(const float* x_in, const int* ei, const float* ea, const int* batch,
                      const float* convW, const float* convB,
                      const float* fcW1, const float* fcb1,
                      const float* fcW, const float* fcb,
                      float* deg, float* enorm, float* xw, float* xc,
                      float* hpool, int* start, float* hout, hipStream_t stream) {
    const int* src = ei;
    const int* dst = ei + NE;
    k_deg_init<<<(NN + 255) / 256, 256, 0, stream>>>(deg);
    k_deg_acc<<<(NE + 255) / 256, 256, 0, stream>>>(dst, ea, deg);
    k_dinv<<<(NN + 255) / 256, 256, 0, stream>>>(deg);
    k_enorm<<<(NE + 255) / 256, 256, 0, stream>>>(src, dst, ea, deg, enorm);
    k_bounds<<<1, NG + 1, 0, stream>>>(batch, start);

    const float* xin = x_in;
    for (int l = 0; l < 6; ++l) {
        k_matmul<<<(NN + 63) / 64, 256, 0, stream>>>(xin, convW + l * HID * HID,
                                                     deg, convB + l * HID, xw, xc);
        k_scatter<<<(NE * 32 + 255) / 256, 256, 0, stream>>>(src, dst, enorm, xw, xc);
        if (l < 5 && hActs[l]) k_tanh<<<(NN * 32 + 255) / 256, 256, 0, stream>>>(xc);
        xin = xc;
    }
    k_pool<<<NG, HID, 0, stream>>>(xc, start, hpool);
    k_fc<<<1, 256, 0, stream>>>(hpool, fcW1, fcb1, fcW, fcb, hout);
}

extern "C" void kernel_launch(void* const* d_in, const int* in_sizes, int n_in,
                              void* d_out, int out_size, void* d_ws, size_t ws_size,
                              hipStream_t stream) {
    const float* x1  = (const float*)d_in[0];
    const int*   ei1 = (const int*)d_in[1];
    const float* ea1 = (const float*)d_in[2];
    const int*   b1  = (const int*)d_in[3];
    const float* x2  = (const float*)d_in[4];
    const int*   ei2 = (const int*)d_in[5];
    const float* ea2 = (const float*)d_in[6];
    const int*   b2  = (const int*)d_in[7];
    const float* convW = (const float*)d_in[8];
    const float* convB = (const float*)d_in[9];
    const float* fcW1  = (const float*)d_in[10];
    const float* fcb1  = (const float*)d_in[11];
    const float* fcW   = (const float*)d_in[12];
    const float* fcb   = (const float*)d_in[13];
    float* out = (float*)d_out;

    // workspace layout (floats)
    float* f     = (float*)d_ws;
    float* deg   = f;                         // NN
    float* enorm = deg + NN;                  // NE
    float* xw    = enorm + NE;                // NN*HID
    float* xc    = xw + (size_t)NN * HID;     // NN*HID
    float* hpool = xc + (size_t)NN * HID;     // NG*HID
    float* h1    = hpool + NG * HID;          // NG*OUT
    float* h2    = h1 + NG * OUT;             // NG*OUT
    int*   start = (int*)(h2 + NG * OUT);     // NG+1

    run_tower(x1, ei1, ea1, b1, convW, convB, fcW1, fcb1, fcW, fcb,
              deg, enorm, xw, xc, hpool, start, h1, stream);
    run_tower(x2, ei2, ea2, b2, convW, convB, fcW1, fcb1, fcW, fcb,
              deg, enorm, xw, xc, hpool, start, h2, stream);
    k_dist<<<1, NG, 0, stream>>>(h1, h2, out);
}

// Round 6
// 7396.064 us; speedup vs baseline: 5.1383x; 5.1383x over previous
//
#include <hip/hip_runtime.h>
#include <math.h>

// Problem constants (match reference)
constexpr int NN  = 100000;   // nodes
constexpr int NE  = 1600000;  // edges
constexpr int NG  = 64;       // graphs
constexpr int HID = 128;
constexpr int OUT = 64;
constexpr int SCAN_B = 256;
constexpr int NBLK = (NN + SCAN_B - 1) / SCAN_B;  // 391
// ACTS = [True, True, False, True, True, True]
static const bool hActs[6] = {true, true, false, true, true, true};

// ---------------- degree / norm precompute ----------------
__global__ void k_deg_init(float* deg) {
    int i = blockIdx.x * 256 + threadIdx.x;
    if (i < NN) deg[i] = 1.0f;  // self-loop weight
}

__global__ void k_deg_acc(const int* __restrict__ dst, const float* __restrict__ ew,
                          float* deg) {
    int e = blockIdx.x * 256 + threadIdx.x;
    if (e < NE) atomicAdd(&deg[dst[e]], ew[e]);
}

__global__ void k_dinv(float* deg) {
    int i = blockIdx.x * 256 + threadIdx.x;
    if (i < NN) {
        float d = deg[i];
        deg[i] = (d > 0.f) ? (1.0f / sqrtf(d)) : 0.0f;
    }
}

// ---------------- CSR build (once per tower, amortized over 6 layers) ----------
__global__ void k_zero_int(int* __restrict__ p, int n) {
    int i = blockIdx.x * 256 + threadIdx.x;
    if (i < n) p[i] = 0;
}

__global__ void k_count(const int* __restrict__ dst, int* __restrict__ cnt) {
    int e = blockIdx.x * 256 + threadIdx.x;
    if (e < NE) atomicAdd(&cnt[dst[e]], 1);
}

// block-level inclusive scan of cnt -> rowptr[i+1], block sums -> bsum
__global__ __launch_bounds__(SCAN_B) void k_scan_block(const int* __restrict__ cnt,
                                                       int* __restrict__ rowptr,
                                                       int* __restrict__ bsum) {
    __shared__ int s[SCAN_B];
    int i = blockIdx.x * SCAN_B + threadIdx.x;
    int v = (i < NN) ? cnt[i] : 0;
    s[threadIdx.x] = v;
    __syncthreads();
    for (int off = 1; off < SCAN_B; off <<= 1) {
        int x = (threadIdx.x >= off) ? s[threadIdx.x - off] : 0;
        __syncthreads();
        s[threadIdx.x] += x;
        __syncthreads();
    }
    if (i < NN) rowptr[i + 1] = s[threadIdx.x];
    if (threadIdx.x == SCAN_B - 1) bsum[blockIdx.x] = s[threadIdx.x];
}

__global__ void k_scan_partial(int* __restrict__ bsum) {
    if (threadIdx.x == 0) {
        int acc = 0;
        for (int b = 0; b < NBLK; ++b) { int v = bsum[b]; bsum[b] = acc; acc += v; }
    }
}

__global__ void k_scan_add(const int* __restrict__ bsum, int* __restrict__ rowptr) {
    int i = blockIdx.x * SCAN_B + threadIdx.x;
    if (i < NN) rowptr[i + 1] += bsum[blockIdx.x];
    if (i == 0) rowptr[0] = 0;
}

__global__ void k_cursor(const int* __restrict__ rowptr, int* __restrict__ cursor) {
    int i = blockIdx.x * 256 + threadIdx.x;
    if (i < NN) cursor[i] = rowptr[i];
}

// fill CSR: edge weight norm computed inline (f32, matches ref's norm array)
__global__ void k_csr_fill(const int* __restrict__ src, const int* __restrict__ dst,
                           const float* __restrict__ ew, const float* __restrict__ dinv,
                           int* __restrict__ cursor, int* __restrict__ csr_src,
                           float* __restrict__ csr_w) {
    int e = blockIdx.x * 256 + threadIdx.x;
    if (e >= NE) return;
    int s = src[e], d = dst[e];
    float w = dinv[s] * ew[e] * dinv[d];
    int pos = atomicAdd(&cursor[d], 1);
    csr_src[pos] = s;
    csr_w[pos] = w;
}

// Graph start offsets via binary search (batch is sorted)
__global__ void k_bounds(const int* __restrict__ batch, int* __restrict__ start) {
    int g = threadIdx.x;  // 0..NG inclusive
    if (g > NG) return;
    int lo = 0, hi = NN;
    while (lo < hi) {
        int mid = (lo + hi) >> 1;
        if (batch[mid] < g) lo = mid + 1; else hi = mid;
    }
    start[g] = lo;
}

// ---------------- per-layer kernels ----------------
// xw[N,128] = x[N,128] @ W[128,128]; W staged in LDS (exactly 64KB)
__global__ __launch_bounds__(256) void k_matmul(const float* __restrict__ x,
                                                const float* __restrict__ W,
                                                float* __restrict__ xw) {
    __shared__ float Ws[HID * HID];
    for (int i = threadIdx.x; i < HID * HID; i += 256) Ws[i] = W[i];
    __syncthreads();
    const int col  = threadIdx.x & 127;
    const int half = threadIdx.x >> 7;  // 0/1
    const int r0 = blockIdx.x * 64;
    const int rend = (r0 + 64 < NN) ? (r0 + 64) : NN;
    for (int r = r0 + half; r < rend; r += 2) {
        const float* xr = x + (size_t)r * HID;
        float acc = 0.f;
#pragma unroll
        for (int k = 0; k < HID; k += 4) {
            float4 xv = *(const float4*)(xr + k);  // broadcast across col-threads
            acc += xv.x * Ws[(k + 0) * HID + col];
            acc += xv.y * Ws[(k + 1) * HID + col];
            acc += xv.z * Ws[(k + 2) * HID + col];
            acc += xv.w * Ws[(k + 3) * HID + col];
        }
        xw[(size_t)r * HID + col] = acc;
    }
}

// CSR gather: xc[n] = act( sum_{e in in(n)} w_e * xw[src_e] + dinv[n]^2*xw[n] + B )
// 32 threads per node, float4 per thread, double accumulation (order-independent).
__global__ __launch_bounds__(256) void k_gather(const float* __restrict__ xw,
                                                const int* __restrict__ rowptr,
                                                const int* __restrict__ csr_src,
                                                const float* __restrict__ csr_w,
                                                const float* __restrict__ dinv,
                                                const float* __restrict__ B,
                                                float* __restrict__ xc, int act) {
    int t = blockIdx.x * 256 + threadIdx.x;
    int n = t >> 5;
    if (n >= NN) return;
    int q = t & 31;
    const float4* xw4 = (const float4*)xw;
    // self-loop term: norm = dinv[n]*1*dinv[n] computed in f32 like the reference
    float d = dinv[n];
    float nself = d * d;
    float4 sv = xw4[(size_t)n * 32 + q];
    double a0 = (double)nself * (double)sv.x;
    double a1 = (double)nself * (double)sv.y;
    double a2 = (double)nself * (double)sv.z;
    double a3 = (double)nself * (double)sv.w;
    int e1 = rowptr[n + 1];
    for (int e = rowptr[n]; e < e1; ++e) {
        int s = csr_src[e];
        double w = (double)csr_w[e];
        float4 v = xw4[(size_t)s * 32 + q];
        a0 += w * (double)v.x;
        a1 += w * (double)v.y;
        a2 += w * (double)v.z;
        a3 += w * (double)v.w;
    }
    float4 b4 = ((const float4*)B)[q];
    float4 o;
    o.x = (float)a0 + b4.x;
    o.y = (float)a1 + b4.y;
    o.z = (float)a2 + b4.z;
    o.w = (float)a3 + b4.w;
    if (act) {
        o.x = tanhf(o.x); o.y = tanhf(o.y); o.z = tanhf(o.z); o.w = tanhf(o.w);
    }
    ((float4*)xc)[(size_t)n * 32 + q] = o;
}

// mean-pool per graph (tanh already applied in layer-5 gather)
__global__ void k_pool(const float* __restrict__ x, const int* __restrict__ start,
                       float* __restrict__ h) {
    int g = blockIdx.x;
    int c = threadIdx.x;  // 128 threads
    int s = start[g], e = start[g + 1];
    float acc = 0.f;
#pragma unroll 4
    for (int n = s; n < e; ++n) acc += x[(size_t)n * HID + c];
    float cnt = (float)(e - s);
    h[g * HID + c] = acc / fmaxf(cnt, 1.0f);
}

// whole FC stack in one block
__global__ __launch_bounds__(256) void k_fc(const float* __restrict__ hpool,
                                            const float* __restrict__ fcW1,
                                            const float* __restrict__ fcb1,
                                            const float* __restrict__ fcW,
                                            const float* __restrict__ fcb,
                                            float* __restrict__ hout) {
    __shared__ float ha[NG * HID];  // 32KB
    __shared__ float hb[NG * OUT];  // 16KB
    for (int i = threadIdx.x; i < NG * HID; i += 256) ha[i] = hpool[i];
    __syncthreads();
    // FC1: [64,128] @ [128,64] + b, relu
    for (int idx = threadIdx.x; idx < NG * OUT; idx += 256) {
        int g = idx >> 6, o = idx & 63;
        float acc = fcb1[o];
        for (int k = 0; k < HID; ++k) acc += ha[g * HID + k] * fcW1[k * OUT + o];
        hb[idx] = fmaxf(acc, 0.f);
    }
    __syncthreads();
    // 5 x [64,64] @ [64,64] + b, relu; ping-pong hb -> ha -> hb ...
    for (int l = 0; l < 5; ++l) {
        const float* in = (l & 1) ? ha : hb;
        float* outb     = (l & 1) ? hb : ha;
        const float* W = fcW + l * OUT * OUT;
        const float* b = fcb + l * OUT;
        for (int idx = threadIdx.x; idx < NG * OUT; idx += 256) {
            int g = idx >> 6, o = idx & 63;
            float acc = b[o];
            for (int k = 0; k < OUT; ++k) acc += in[g * OUT + k] * W[k * OUT + o];
            outb[idx] = fmaxf(acc, 0.f);
        }
        __syncthreads();
    }
    for (int idx = threadIdx.x; idx < NG * OUT; idx += 256) hout[idx] = ha[idx];
}

__global__ void k_dist(const float* __restrict__ h1, const float* __restrict__ h2,
                       float* __restrict__ out) {
    int g = threadIdx.x;  // 64
    if (g >= NG) return;
    float acc = 0.f;
    for (int c = 0; c < OUT; ++c) {
        float d = h1[g * OUT + c] - h2[g * OUT + c];
        acc += d * d;
    }
    out[g] = sqrtf(acc);
}

// ---------------- host-side tower driver ----------------
static void run_tower(const float* x_in, const int* ei, const float* ea, const int* batch,
                      const float* convW, const float* convB,
                      const float* fcW1, const float* fcb1,
                      const float* fcW, const float* fcb,
                      float* deg, int* rowptr, int* cursor, int* cnt, int* bsum,
                      int* csr_src, float* csr_w, float* xw, float* xc,
                      float* hpool, int* start, float* hout, hipStream_t stream) {
    const int* src = ei;
    const int* dst = ei + NE;
    const int gE = (NE + 255) / 256;
    const int gN = (NN + 255) / 256;
    // degree + dinv
    k_deg_init<<<gN, 256, 0, stream>>>(deg);
    k_deg_acc<<<gE, 256, 0, stream>>>(dst, ea, deg);
    k_dinv<<<gN, 256, 0, stream>>>(deg);
    // CSR build
    k_zero_int<<<gN, 256, 0, stream>>>(cnt, NN);
    k_count<<<gE, 256, 0, stream>>>(dst, cnt);
    k_scan_block<<<NBLK, SCAN_B, 0, stream>>>(cnt, rowptr, bsum);
    k_scan_partial<<<1, 64, 0, stream>>>(bsum);
    k_scan_add<<<NBLK, SCAN_B, 0, stream>>>(bsum, rowptr);
    k_cursor<<<gN, 256, 0, stream>>>(rowptr, cursor);
    k_csr_fill<<<gE, 256, 0, stream>>>(src, dst, ea, deg, cursor, csr_src, csr_w);
    k_bounds<<<1, NG + 1, 0, stream>>>(batch, start);

    const float* xin = x_in;
    for (int l = 0; l < 6; ++l) {
        k_matmul<<<(NN + 63) / 64, 256, 0, stream>>>(xin, convW + l * HID * HID, xw);
        k_gather<<<(NN * 32 + 255) / 256, 256, 0, stream>>>(xw, rowptr, csr_src, csr_w,
                                                            deg, convB + l * HID, xc,
                                                            hActs[l] ? 1 : 0);
        xin = xc;
    }
    k_pool<<<NG, HID, 0, stream>>>(xc, start, hpool);
    k_fc<<<1, 256, 0, stream>>>(hpool, fcW1, fcb1, fcW, fcb, hout);
}

extern "C" void kernel_launch(void* const* d_in, const int* in_sizes, int n_in,
                              void* d_out, int out_size, void* d_ws, size_t ws_size,
                              hipStream_t stream) {
    const float* x1  = (const float*)d_in[0];
    const int*   ei1 = (const int*)d_in[1];
    const float* ea1 = (const float*)d_in[2];
    const int*   b1  = (const int*)d_in[3];
    const float* x2  = (const float*)d_in[4];
    const int*   ei2 = (const int*)d_in[5];
    const float* ea2 = (const float*)d_in[6];
    const int*   b2  = (const int*)d_in[7];
    const float* convW = (const float*)d_in[8];
    const float* convB = (const float*)d_in[9];
    const float* fcW1  = (const float*)d_in[10];
    const float* fcb1  = (const float*)d_in[11];
    const float* fcW   = (const float*)d_in[12];
    const float* fcb   = (const float*)d_in[13];
    float* out = (float*)d_out;

    // workspace layout (4-byte units)
    float* f      = (float*)d_ws;
    float* deg    = f;                          // NN floats (becomes dinv)
    float* csr_w  = deg + NN;                   // NE floats
    float* xw     = csr_w + NE;                 // NN*HID
    float* xc     = xw + (size_t)NN * HID;      // NN*HID
    float* hpool  = xc + (size_t)NN * HID;      // NG*HID
    float* h1     = hpool + NG * HID;           // NG*OUT
    float* h2     = h1 + NG * OUT;              // NG*OUT
    int*   rowptr = (int*)(h2 + NG * OUT);      // NN+1
    int*   cursor = rowptr + NN + 1;            // NN
    int*   cnt    = cursor + NN;                // NN
    int*   bsum   = cnt + NN;                   // NBLK
    int*   csr_src= bsum + NBLK;                // NE
    int*   start  = csr_src + NE;               // NG+1

    run_tower(x1, ei1, ea1, b1, convW, convB, fcW1, fcb1, fcW, fcb,
              deg, rowptr, cursor, cnt, bsum, csr_src, csr_w, xw, xc,
              hpool, start, h1, stream);
    run_tower(x2, ei2, ea2, b2, convW, convB, fcW1, fcb1, fcW, fcb,
              deg, rowptr, cursor, cnt, bsum, csr_src, csr_w, xw, xc,
              hpool, start, h2, stream);
    k_dist<<<1, NG, 0, stream>>>(h1, h2, out);
}

// Round 7
// 4993.898 us; speedup vs baseline: 7.6100x; 1.4810x over previous
//
#include <hip/hip_runtime.h>
#include <math.h>

// Problem constants (match reference)
constexpr int NN  = 100000;   // nodes
constexpr int NE  = 1600000;  // edges
constexpr int NG  = 64;       // graphs
constexpr int HID = 128;
constexpr int OUT = 64;
constexpr int SCAN_B = 256;
constexpr int NBLK = (NN + SCAN_B - 1) / SCAN_B;  // 391
// ACTS = [True, True, False, True, True, True]
static const bool hActs[6] = {true, true, false, true, true, true};

// ---------------- degree / norm precompute ----------------
__global__ void k_deg_init(float* deg) {
    int i = blockIdx.x * 256 + threadIdx.x;
    if (i < NN) deg[i] = 1.0f;  // self-loop weight
}

__global__ void k_deg_acc(const int* __restrict__ dst, const float* __restrict__ ew,
                          float* deg) {
    int e = blockIdx.x * 256 + threadIdx.x;
    if (e < NE) atomicAdd(&deg[dst[e]], ew[e]);
}

__global__ void k_dinv(float* deg) {
    int i = blockIdx.x * 256 + threadIdx.x;
    if (i < NN) {
        float d = deg[i];
        deg[i] = (d > 0.f) ? (1.0f / sqrtf(d)) : 0.0f;
    }
}

// ---------------- CSR build (once per tower, amortized over 6 layers) ----------
__global__ void k_zero_int(int* __restrict__ p, int n) {
    int i = blockIdx.x * 256 + threadIdx.x;
    if (i < n) p[i] = 0;
}

__global__ void k_count(const int* __restrict__ dst, int* __restrict__ cnt) {
    int e = blockIdx.x * 256 + threadIdx.x;
    if (e < NE) atomicAdd(&cnt[dst[e]], 1);
}

// block-level inclusive scan of cnt -> rowptr[i+1], block sums -> bsum
__global__ __launch_bounds__(SCAN_B) void k_scan_block(const int* __restrict__ cnt,
                                                       int* __restrict__ rowptr,
                                                       int* __restrict__ bsum) {
    __shared__ int s[SCAN_B];
    int i = blockIdx.x * SCAN_B + threadIdx.x;
    int v = (i < NN) ? cnt[i] : 0;
    s[threadIdx.x] = v;
    __syncthreads();
    for (int off = 1; off < SCAN_B; off <<= 1) {
        int x = (threadIdx.x >= off) ? s[threadIdx.x - off] : 0;
        __syncthreads();
        s[threadIdx.x] += x;
        __syncthreads();
    }
    if (i < NN) rowptr[i + 1] = s[threadIdx.x];
    if (threadIdx.x == SCAN_B - 1) bsum[blockIdx.x] = s[threadIdx.x];
}

__global__ void k_scan_partial(int* __restrict__ bsum) {
    if (threadIdx.x == 0) {
        int acc = 0;
        for (int b = 0; b < NBLK; ++b) { int v = bsum[b]; bsum[b] = acc; acc += v; }
    }
}

__global__ void k_scan_add(const int* __restrict__ bsum, int* __restrict__ rowptr) {
    int i = blockIdx.x * SCAN_B + threadIdx.x;
    if (i < NN) rowptr[i + 1] += bsum[blockIdx.x];
    if (i == 0) rowptr[0] = 0;
}

__global__ void k_cursor(const int* __restrict__ rowptr, int* __restrict__ cursor) {
    int i = blockIdx.x * 256 + threadIdx.x;
    if (i < NN) cursor[i] = rowptr[i];
}

// fill CSR: edge weight norm computed inline (f32, matches ref's norm array)
__global__ void k_csr_fill(const int* __restrict__ src, const int* __restrict__ dst,
                           const float* __restrict__ ew, const float* __restrict__ dinv,
                           int* __restrict__ cursor, int* __restrict__ csr_src,
                           float* __restrict__ csr_w) {
    int e = blockIdx.x * 256 + threadIdx.x;
    if (e >= NE) return;
    int s = src[e], d = dst[e];
    float w = dinv[s] * ew[e] * dinv[d];
    int pos = atomicAdd(&cursor[d], 1);
    csr_src[pos] = s;
    csr_w[pos] = w;
}

// Graph start offsets via binary search (batch is sorted)
__global__ void k_bounds(const int* __restrict__ batch, int* __restrict__ start) {
    int g = threadIdx.x;  // 0..NG inclusive
    if (g > NG) return;
    int lo = 0, hi = NN;
    while (lo < hi) {
        int mid = (lo + hi) >> 1;
        if (batch[mid] < g) lo = mid + 1; else hi = mid;
    }
    start[g] = lo;
}

// ---------------- per-layer kernels ----------------
// xw[N,128] = x[N,128] @ W[128,128].
// 16 rows/block, 256 threads: thread = (col 0..127, rh 0..1), 8 rows/thread.
// W staged in two 32KB halves (occupancy: 5 blocks/CU); 8 independent
// accumulators/thread (ILP 8). W LDS reads are bank-conflict-free (col%32,
// 2 lanes/bank). x reads are wave-broadcast float4 (same addr all lanes).
__global__ __launch_bounds__(256) void k_matmul(const float* __restrict__ x,
                                                const float* __restrict__ W,
                                                float* __restrict__ xw) {
    __shared__ float Ws[64 * HID];  // 32KB: one k-half of W
    const int col = threadIdx.x & 127;
    const int rh  = threadIdx.x >> 7;  // 0/1
    const int rbase = blockIdx.x * 16 + rh * 8;
    const float4* x4 = (const float4*)x;
    float acc[8];
#pragma unroll
    for (int j = 0; j < 8; ++j) acc[j] = 0.f;

    for (int kh = 0; kh < 2; ++kh) {
        __syncthreads();  // protect Ws before overwrite (kh=1); harmless at kh=0
        for (int i = threadIdx.x; i < 64 * HID; i += 256)
            Ws[i] = W[kh * 64 * HID + i];
        __syncthreads();
        const int kbase = kh * 16;  // float4 index base into a row of x
#pragma unroll 2
        for (int ks = 0; ks < 16; ++ks) {
            float w0 = Ws[(ks * 4 + 0) * HID + col];
            float w1 = Ws[(ks * 4 + 1) * HID + col];
            float w2 = Ws[(ks * 4 + 2) * HID + col];
            float w3 = Ws[(ks * 4 + 3) * HID + col];
#pragma unroll
            for (int j = 0; j < 8; ++j) {
                float4 xv = x4[(size_t)(rbase + j) * 32 + kbase + ks];
                acc[j] += xv.x * w0 + xv.y * w1 + xv.z * w2 + xv.w * w3;
            }
        }
    }
#pragma unroll
    for (int j = 0; j < 8; ++j)
        xw[(size_t)(rbase + j) * HID + col] = acc[j];
}

// CSR gather: xc[n] = act( sum_{e in in(n)} w_e * xw[src_e] + dinv[n]^2*xw[n] + B )
// 32 threads per node, float4 per thread, double accumulation (order-independent).
__global__ __launch_bounds__(256) void k_gather(const float* __restrict__ xw,
                                                const int* __restrict__ rowptr,
                                                const int* __restrict__ csr_src,
                                                const float* __restrict__ csr_w,
                                                const float* __restrict__ dinv,
                                                const float* __restrict__ B,
                                                float* __restrict__ xc, int act) {
    int t = blockIdx.x * 256 + threadIdx.x;
    int n = t >> 5;
    if (n >= NN) return;
    int q = t & 31;
    const float4* xw4 = (const float4*)xw;
    float d = dinv[n];
    float nself = d * d;
    float4 sv = xw4[(size_t)n * 32 + q];
    double a0 = (double)nself * (double)sv.x;
    double a1 = (double)nself * (double)sv.y;
    double a2 = (double)nself * (double)sv.z;
    double a3 = (double)nself * (double)sv.w;
    int e1 = rowptr[n + 1];
    for (int e = rowptr[n]; e < e1; ++e) {
        int s = csr_src[e];
        double w = (double)csr_w[e];
        float4 v = xw4[(size_t)s * 32 + q];
        a0 += w * (double)v.x;
        a1 += w * (double)v.y;
        a2 += w * (double)v.z;
        a3 += w * (double)v.w;
    }
    float4 b4 = ((const float4*)B)[q];
    float4 o;
    o.x = (float)a0 + b4.x;
    o.y = (float)a1 + b4.y;
    o.z = (float)a2 + b4.z;
    o.w = (float)a3 + b4.w;
    if (act) {
        o.x = tanhf(o.x); o.y = tanhf(o.y); o.z = tanhf(o.z); o.w = tanhf(o.w);
    }
    ((float4*)xc)[(size_t)n * 32 + q] = o;
}

// mean-pool per graph (tanh already applied in layer-5 gather)
__global__ void k_pool(const float* __restrict__ x, const int* __restrict__ start,
                       float* __restrict__ h) {
    int g = blockIdx.x;
    int c = threadIdx.x;  // 128 threads
    int s = start[g], e = start[g + 1];
    float acc = 0.f;
#pragma unroll 4
    for (int n = s; n < e; ++n) acc += x[(size_t)n * HID + c];
    float cnt = (float)(e - s);
    h[g * HID + c] = acc / fmaxf(cnt, 1.0f);
}

// whole FC stack in one block
__global__ __launch_bounds__(256) void k_fc(const float* __restrict__ hpool,
                                            const float* __restrict__ fcW1,
                                            const float* __restrict__ fcb1,
                                            const float* __restrict__ fcW,
                                            const float* __restrict__ fcb,
                                            float* __restrict__ hout) {
    __shared__ float ha[NG * HID];  // 32KB
    __shared__ float hb[NG * OUT];  // 16KB
    for (int i = threadIdx.x; i < NG * HID; i += 256) ha[i] = hpool[i];
    __syncthreads();
    // FC1: [64,128] @ [128,64] + b, relu
    for (int idx = threadIdx.x; idx < NG * OUT; idx += 256) {
        int g = idx >> 6, o = idx & 63;
        float acc = fcb1[o];
        for (int k = 0; k < HID; ++k) acc += ha[g * HID + k] * fcW1[k * OUT + o];
        hb[idx] = fmaxf(acc, 0.f);
    }
    __syncthreads();
    // 5 x [64,64] @ [64,64] + b, relu; ping-pong hb -> ha -> hb ...
    for (int l = 0; l < 5; ++l) {
        const float* in = (l & 1) ? ha : hb;
        float* outb     = (l & 1) ? hb : ha;
        const float* W = fcW + l * OUT * OUT;
        const float* b = fcb + l * OUT;
        for (int idx = threadIdx.x; idx < NG * OUT; idx += 256) {
            int g = idx >> 6, o = idx & 63;
            float acc = b[o];
            for (int k = 0; k < OUT; ++k) acc += in[g * OUT + k] * W[k * OUT + o];
            outb[idx] = fmaxf(acc, 0.f);
        }
        __syncthreads();
    }
    for (int idx = threadIdx.x; idx < NG * OUT; idx += 256) hout[idx] = ha[idx];
}

__global__ void k_dist(const float* __restrict__ h1, const float* __restrict__ h2,
                       float* __restrict__ out) {
    int g = threadIdx.x;  // 64
    if (g >= NG) return;
    float acc = 0.f;
    for (int c = 0; c < OUT; ++c) {
        float d = h1[g * OUT + c] - h2[g * OUT + c];
        acc += d * d;
    }
    out[g] = sqrtf(acc);
}

// ---------------- host-side tower driver ----------------
static void run_tower(const float* x_in, const int* ei, const float* ea, const int* batch,
                      const float* convW, const float* convB,
                      const float* fcW1, const float* fcb1,
                      const float* fcW, const float* fcb,
                      float* deg, int* rowptr, int* cursor, int* cnt, int* bsum,
                      int* csr_src, float* csr_w, float* xw, float* xc,
                      float* hpool, int* start, float* hout, hipStream_t stream) {
    const int* src = ei;
    const int* dst = ei + NE;
    const int gE = (NE + 255) / 256;
    const int gN = (NN + 255) / 256;
    // degree + dinv
    k_deg_init<<<gN, 256, 0, stream>>>(deg);
    k_deg_acc<<<gE, 256, 0, stream>>>(dst, ea, deg);
    k_dinv<<<gN, 256, 0, stream>>>(deg);
    // CSR build
    k_zero_int<<<gN, 256, 0, stream>>>(cnt, NN);
    k_count<<<gE, 256, 0, stream>>>(dst, cnt);
    k_scan_block<<<NBLK, SCAN_B, 0, stream>>>(cnt, rowptr, bsum);
    k_scan_partial<<<1, 64, 0, stream>>>(bsum);
    k_scan_add<<<NBLK, SCAN_B, 0, stream>>>(bsum, rowptr);
    k_cursor<<<gN, 256, 0, stream>>>(rowptr, cursor);
    k_csr_fill<<<gE, 256, 0, stream>>>(src, dst, ea, deg, cursor, csr_src, csr_w);
    k_bounds<<<1, NG + 1, 0, stream>>>(batch, start);

    const float* xin = x_in;
    for (int l = 0; l < 6; ++l) {
        k_matmul<<<NN / 16, 256, 0, stream>>>(xin, convW + l * HID * HID, xw);
        k_gather<<<(NN * 32 + 255) / 256, 256, 0, stream>>>(xw, rowptr, csr_src, csr_w,
                                                            deg, convB + l * HID, xc,
                                                            hActs[l] ? 1 : 0);
        xin = xc;
    }
    k_pool<<<NG, HID, 0, stream>>>(xc, start, hpool);
    k_fc<<<1, 256, 0, stream>>>(hpool, fcW1, fcb1, fcW, fcb, hout);
}

extern "C" void kernel_launch(void* const* d_in, const int* in_sizes, int n_in,
                              void* d_out, int out_size, void* d_ws, size_t ws_size,
                              hipStream_t stream) {
    const float* x1  = (const float*)d_in[0];
    const int*   ei1 = (const int*)d_in[1];
    const float* ea1 = (const float*)d_in[2];
    const int*   b1  = (const int*)d_in[3];
    const float* x2  = (const float*)d_in[4];
    const int*   ei2 = (const int*)d_in[5];
    const float* ea2 = (const float*)d_in[6];
    const int*   b2  = (const int*)d_in[7];
    const float* convW = (const float*)d_in[8];
    const float* convB = (const float*)d_in[9];
    const float* fcW1  = (const float*)d_in[10];
    const float* fcb1  = (const float*)d_in[11];
    const float* fcW   = (const float*)d_in[12];
    const float* fcb   = (const float*)d_in[13];
    float* out = (float*)d_out;

    // workspace layout (4-byte units)
    float* f      = (float*)d_ws;
    float* deg    = f;                          // NN floats (becomes dinv)
    float* csr_w  = deg + NN;                   // NE floats
    float* xw     = csr_w + NE;                 // NN*HID
    float* xc     = xw + (size_t)NN * HID;      // NN*HID
    float* hpool  = xc + (size_t)NN * HID;      // NG*HID
    float* h1     = hpool + NG * HID;           // NG*OUT
    float* h2     = h1 + NG * OUT;              // NG*OUT
    int*   rowptr = (int*)(h2 + NG * OUT);      // NN+1
    int*   cursor = rowptr + NN + 1;            // NN
    int*   cnt    = cursor + NN;                // NN
    int*   bsum   = cnt + NN;                   // NBLK
    int*   csr_src= bsum + NBLK;                // NE
    int*   start  = csr_src + NE;               // NG+1

    run_tower(x1, ei1, ea1, b1, convW, convB, fcW1, fcb1, fcW, fcb,
              deg, rowptr, cursor, cnt, bsum, csr_src, csr_w, xw, xc,
              hpool, start, h1, stream);
    run_tower(x2, ei2, ea2, b2, convW, convB, fcW1, fcb1, fcW, fcb,
              deg, rowptr, cursor, cnt, bsum, csr_src, csr_w, xw, xc,
              hpool, start, h2, stream);
    k_dist<<<1, NG, 0, stream>>>(h1, h2, out);
}

// Round 12
// 2976.848 us; speedup vs baseline: 12.7664x; 1.6776x over previous
//
#include <hip/hip_runtime.h>
#include <math.h>

// Problem constants (match reference)
constexpr int NN  = 100000;   // nodes
constexpr int NE  = 1600000;  // edges
constexpr int NG  = 64;       // graphs
constexpr int HID = 128;
constexpr int OUT = 64;
constexpr int SCAN_B = 256;
constexpr int NBLK = (NN + SCAN_B - 1) / SCAN_B;  // 391
// ACTS = [True, True, False, True, True, True]
static const bool hActs[6] = {true, true, false, true, true, true};

typedef __attribute__((ext_vector_type(8))) short short8;   // 8 bf16 (4 VGPRs)
typedef __attribute__((ext_vector_type(4))) float f32x4;    // MFMA C/D frag

__device__ __forceinline__ unsigned short f32_to_bf16_rne(float f) {
    unsigned int u = __float_as_uint(f);
    unsigned int r = (u + 0x7fffu + ((u >> 16) & 1u)) >> 16;
    return (unsigned short)r;
}
__device__ __forceinline__ float bf16_to_f32(unsigned short h) {
    return __uint_as_float(((unsigned int)h) << 16);
}

// ---------------- degree / norm precompute ----------------
__global__ void k_deg_init(float* deg) {
    int i = blockIdx.x * 256 + threadIdx.x;
    if (i < NN) deg[i] = 1.0f;  // self-loop weight
}

__global__ void k_deg_acc(const int* __restrict__ dst, const float* __restrict__ ew,
                          float* deg) {
    int e = blockIdx.x * 256 + threadIdx.x;
    if (e < NE) atomicAdd(&deg[dst[e]], ew[e]);
}

__global__ void k_dinv(float* deg) {
    int i = blockIdx.x * 256 + threadIdx.x;
    if (i < NN) {
        float d = deg[i];
        deg[i] = (d > 0.f) ? (1.0f / sqrtf(d)) : 0.0f;
    }
}

// ---------------- W fragment pre-swizzle (once per launch, shared towers) ----
// Fragment-ordered bf16 hi/lo of all 6 conv layers.
// t = ((((l*4 + kc)*8 + ct)*64 + lane)*8 + j
// maps to W[l][kc*32 + (lane>>4)*8 + j][ct*16 + (lane&15)]
__global__ void k_wprep(const float* __restrict__ convW,
                        unsigned short* __restrict__ Whi,
                        unsigned short* __restrict__ Wlo) {
    int t = blockIdx.x * 256 + threadIdx.x;
    if (t >= 6 * 16384) return;
    int j    = t & 7;
    int lane = (t >> 3) & 63;
    int ct   = (t >> 9) & 7;
    int kc   = (t >> 12) & 3;
    int l    = t >> 14;
    int k = kc * 32 + (lane >> 4) * 8 + j;
    int c = ct * 16 + (lane & 15);
    float w = convW[((size_t)l * HID + k) * HID + c];
    unsigned short h = f32_to_bf16_rne(w);
    Whi[t] = h;
    Wlo[t] = f32_to_bf16_rne(w - bf16_to_f32(h));
}

// ---------------- CSR build (once per tower, amortized over 6 layers) ----------
__global__ void k_zero_int(int* __restrict__ p, int n) {
    int i = blockIdx.x * 256 + threadIdx.x;
    if (i < n) p[i] = 0;
}

__global__ void k_count(const int* __restrict__ dst, int* __restrict__ cnt) {
    int e = blockIdx.x * 256 + threadIdx.x;
    if (e < NE) atomicAdd(&cnt[dst[e]], 1);
}

// block-level inclusive scan of cnt -> rowptr[i+1], block sums -> bsum
__global__ __launch_bounds__(SCAN_B) void k_scan_block(const int* __restrict__ cnt,
                                                       int* __restrict__ rowptr,
                                                       int* __restrict__ bsum) {
    __shared__ int s[SCAN_B];
    int i = blockIdx.x * SCAN_B + threadIdx.x;
    int v = (i < NN) ? cnt[i] : 0;
    s[threadIdx.x] = v;
    __syncthreads();
    for (int off = 1; off < SCAN_B; off <<= 1) {
        int x = (threadIdx.x >= off) ? s[threadIdx.x - off] : 0;
        __syncthreads();
        s[threadIdx.x] += x;
        __syncthreads();
    }
    if (i < NN) rowptr[i + 1] = s[threadIdx.x];
    if (threadIdx.x == SCAN_B - 1) bsum[blockIdx.x] = s[threadIdx.x];
}

__global__ void k_scan_partial(int* __restrict__ bsum) {
    if (threadIdx.x == 0) {
        int acc = 0;
        for (int b = 0; b < NBLK; ++b) { int v = bsum[b]; bsum[b] = acc; acc += v; }
    }
}

__global__ void k_scan_add(const int* __restrict__ bsum, int* __restrict__ rowptr) {
    int i = blockIdx.x * SCAN_B + threadIdx.x;
    if (i < NN) rowptr[i + 1] += bsum[blockIdx.x];
    if (i == 0) rowptr[0] = 0;
}

__global__ void k_cursor(const int* __restrict__ rowptr, int* __restrict__ cursor) {
    int i = blockIdx.x * 256 + threadIdx.x;
    if (i < NN) cursor[i] = rowptr[i];
}

// fill CSR: edge weight norm computed inline (f32, matches ref's norm array)
__global__ void k_csr_fill(const int* __restrict__ src, const int* __restrict__ dst,
                           const float* __restrict__ ew, const float* __restrict__ dinv,
                           int* __restrict__ cursor, int* __restrict__ csr_src,
                           float* __restrict__ csr_w) {
    int e = blockIdx.x * 256 + threadIdx.x;
    if (e >= NE) return;
    int s = src[e], d = dst[e];
    float w = dinv[s] * ew[e] * dinv[d];
    int pos = atomicAdd(&cursor[d], 1);
    csr_src[pos] = s;
    csr_w[pos] = w;
}

// Graph start offsets via binary search (batch is sorted)
__global__ void k_bounds(const int* __restrict__ batch, int* __restrict__ start) {
    int g = threadIdx.x;  // 0..NG inclusive
    if (g > NG) return;
    int lo = 0, hi = NN;
    while (lo < hi) {
        int mid = (lo + hi) >> 1;
        if (batch[mid] < g) lo = mid + 1; else hi = mid;
    }
    start[g] = lo;
}

// ---------------- per-layer kernels ----------------
// xw[N,128] = x[N,128] @ W[128,128] via bf16 split-2 MFMA:
//   x@W ~= xhi@Whi + xlo@Whi + xhi@Wlo  (rel err ~2^-18)
// Wave computes 16 rows x 128 cols. A-frags built in-register from f32 x.
// B-frags read from fragment-ordered Whi/Wlo (lane-contiguous 16B, L2-resident).
// Layouts (16x16x32): A row=lane&15,k=(lane>>4)*8+j; B col=lane&15,same k;
// C col=lane&15,row=(lane>>4)*4+reg (m89-verified).
__global__ __launch_bounds__(256) void k_matmul_mfma(const float* __restrict__ x,
                                                     const unsigned short* __restrict__ Whi,
                                                     const unsigned short* __restrict__ Wlo,
                                                     float* __restrict__ xw) {
    const int wid  = threadIdx.x >> 6;
    const int lane = threadIdx.x & 63;
    const long rbase = ((long)blockIdx.x * 4 + wid) * 16;
    if (rbase >= NN) return;
    const int arow = lane & 15;
    const int agrp = lane >> 4;

    f32x4 acc[8];
#pragma unroll
    for (int ct = 0; ct < 8; ++ct) acc[ct] = (f32x4){0.f, 0.f, 0.f, 0.f};

    const float* xr = x + (size_t)(rbase + arow) * HID;
#pragma unroll
    for (int kc = 0; kc < 4; ++kc) {
        float4 v0 = *(const float4*)(xr + kc * 32 + agrp * 8);
        float4 v1 = *(const float4*)(xr + kc * 32 + agrp * 8 + 4);
        float vv[8] = {v0.x, v0.y, v0.z, v0.w, v1.x, v1.y, v1.z, v1.w};
        short8 ahi, alo;
#pragma unroll
        for (int j = 0; j < 8; ++j) {
            unsigned short h = f32_to_bf16_rne(vv[j]);
            ahi[j] = (short)h;
            alo[j] = (short)f32_to_bf16_rne(vv[j] - bf16_to_f32(h));
        }
#pragma unroll
        for (int ct = 0; ct < 8; ++ct) {
            short8 bhi = *(const short8*)(Whi + (((size_t)(kc * 8 + ct)) * 64 + lane) * 8);
            short8 blo = *(const short8*)(Wlo + (((size_t)(kc * 8 + ct)) * 64 + lane) * 8);
            acc[ct] = __builtin_amdgcn_mfma_f32_16x16x32_bf16(ahi, bhi, acc[ct], 0, 0, 0);
            acc[ct] = __builtin_amdgcn_mfma_f32_16x16x32_bf16(alo, bhi, acc[ct], 0, 0, 0);
            acc[ct] = __builtin_amdgcn_mfma_f32_16x16x32_bf16(ahi, blo, acc[ct], 0, 0, 0);
        }
    }
    // C store: row = rbase + agrp*4 + r, col = ct*16 + (lane&15)
#pragma unroll
    for (int ct = 0; ct < 8; ++ct) {
#pragma unroll
        for (int r = 0; r < 4; ++r) {
            xw[(size_t)(rbase + agrp * 4 + r) * HID + ct * 16 + (lane & 15)] = acc[ct][r];
        }
    }
}

// CSR gather: xc[n] = act( sum_{e in in(n)} w_e * xw[src_e] + dinv[n]^2*xw[n] + B )
// 32 threads per node, float4 per thread, double accumulation (order-independent).
__global__ __launch_bounds__(256) void k_gather(const float* __restrict__ xw,
                                                const int* __restrict__ rowptr,
                                                const int* __restrict__ csr_src,
                                                const float* __restrict__ csr_w,
                                                const float* __restrict__ dinv,
                                                const float* __restrict__ B,
                                                float* __restrict__ xc, int act) {
    int t = blockIdx.x * 256 + threadIdx.x;
    int n = t >> 5;
    if (n >= NN) return;
    int q = t & 31;
    const float4* xw4 = (const float4*)xw;
    float d = dinv[n];
    float nself = d * d;
    float4 sv = xw4[(size_t)n * 32 + q];
    double a0 = (double)nself * (double)sv.x;
    double a1 = (double)nself * (double)sv.y;
    double a2 = (double)nself * (double)sv.z;
    double a3 = (double)nself * (double)sv.w;
    int e1 = rowptr[n + 1];
    for (int e = rowptr[n]; e < e1; ++e) {
        int s = csr_src[e];
        double w = (double)csr_w[e];
        float4 v = xw4[(size_t)s * 32 + q];
        a0 += w * (double)v.x;
        a1 += w * (double)v.y;
        a2 += w * (double)v.z;
        a3 += w * (double)v.w;
    }
    float4 b4 = ((const float4*)B)[q];
    float4 o;
    o.x = (float)a0 + b4.x;
    o.y = (float)a1 + b4.y;
    o.z = (float)a2 + b4.z;
    o.w = (float)a3 + b4.w;
    if (act) {
        o.x = tanhf(o.x); o.y = tanhf(o.y); o.z = tanhf(o.z); o.w = tanhf(o.w);
    }
    ((float4*)xc)[(size_t)n * 32 + q] = o;
}

// mean-pool per graph (tanh already applied in layer-5 gather)
__global__ void k_pool(const float* __restrict__ x, const int* __restrict__ start,
                       float* __restrict__ h) {
    int g = blockIdx.x;
    int c = threadIdx.x;  // 128 threads
    int s = start[g], e = start[g + 1];
    float acc = 0.f;
#pragma unroll 4
    for (int n = s; n < e; ++n) acc += x[(size_t)n * HID + c];
    float cnt = (float)(e - s);
    h[g * HID + c] = acc / fmaxf(cnt, 1.0f);
}

// whole FC stack in one block
__global__ __launch_bounds__(256) void k_fc(const float* __restrict__ hpool,
                                            const float* __restrict__ fcW1,
                                            const float* __restrict__ fcb1,
                                            const float* __restrict__ fcW,
                                            const float* __restrict__ fcb,
                                            float* __restrict__ hout) {
    __shared__ float ha[NG * HID];  // 32KB
    __shared__ float hb[NG * OUT];  // 16KB
    for (int i = threadIdx.x; i < NG * HID; i += 256) ha[i] = hpool[i];
    __syncthreads();
    // FC1: [64,128] @ [128,64] + b, relu
    for (int idx = threadIdx.x; idx < NG * OUT; idx += 256) {
        int g = idx >> 6, o = idx & 63;
        float acc = fcb1[o];
        for (int k = 0; k < HID; ++k) acc += ha[g * HID + k] * fcW1[k * OUT + o];
        hb[idx] = fmaxf(acc, 0.f);
    }
    __syncthreads();
    // 5 x [64,64] @ [64,64] + b, relu; ping-pong hb -> ha -> hb ...
    for (int l = 0; l < 5; ++l) {
        const float* in = (l & 1) ? ha : hb;
        float* outb     = (l & 1) ? hb : ha;
        const float* W = fcW + l * OUT * OUT;
        const float* b = fcb + l * OUT;
        for (int idx = threadIdx.x; idx < NG * OUT; idx += 256) {
            int g = idx >> 6, o = idx & 63;
            float acc = b[o];
            for (int k = 0; k < OUT; ++k) acc += in[g * OUT + k] * W[k * OUT + o];
            outb[idx] = fmaxf(acc, 0.f);
        }
        __syncthreads();
    }
    for (int idx = threadIdx.x; idx < NG * OUT; idx += 256) hout[idx] = ha[idx];
}

__global__ void k_dist(const float* __restrict__ h1, const float* __restrict__ h2,
                       float* __restrict__ out) {
    int g = threadIdx.x;  // 64
    if (g >= NG) return;
    float acc = 0.f;
    for (int c = 0; c < OUT; ++c) {
        float d = h1[g * OUT + c] - h2[g * OUT + c];
        acc += d * d;
    }
    out[g] = sqrtf(acc);
}

// ---------------- host-side tower driver ----------------
static void run_tower(const float* x_in, const int* ei, const float* ea, const int* batch,
                      const unsigned short* Whi, const unsigned short* Wlo,
                      const float* convB,
                      const float* fcW1, const float* fcb1,
                      const float* fcW, const float* fcb,
                      float* deg, int* rowptr, int* cursor, int* cnt, int* bsum,
                      int* csr_src, float* csr_w, float* xw, float* xc,
                      float* hpool, int* start, float* hout, hipStream_t stream) {
    const int* src = ei;
    const int* dst = ei + NE;
    const int gE = (NE + 255) / 256;
    const int gN = (NN + 255) / 256;
    // degree + dinv
    k_deg_init<<<gN, 256, 0, stream>>>(deg);
    k_deg_acc<<<gE, 256, 0, stream>>>(dst, ea, deg);
    k_dinv<<<gN, 256, 0, stream>>>(deg);
    // CSR build
    k_zero_int<<<gN, 256, 0, stream>>>(cnt, NN);
    k_count<<<gE, 256, 0, stream>>>(dst, cnt);
    k_scan_block<<<NBLK, SCAN_B, 0, stream>>>(cnt, rowptr, bsum);
    k_scan_partial<<<1, 64, 0, stream>>>(bsum);
    k_scan_add<<<NBLK, SCAN_B, 0, stream>>>(bsum, rowptr);
    k_cursor<<<gN, 256, 0, stream>>>(rowptr, cursor);
    k_csr_fill<<<gE, 256, 0, stream>>>(src, dst, ea, deg, cursor, csr_src, csr_w);
    k_bounds<<<1, NG + 1, 0, stream>>>(batch, start);

    const int gMM = (NN / 16 + 3) / 4;  // 4 wave-tiles (16 rows each) per block
    const float* xin = x_in;
    for (int l = 0; l < 6; ++l) {
        k_matmul_mfma<<<gMM, 256, 0, stream>>>(xin, Whi + l * 16384, Wlo + l * 16384, xw);
        k_gather<<<(NN * 32 + 255) / 256, 256, 0, stream>>>(xw, rowptr, csr_src, csr_w,
                                                            deg, convB + l * HID, xc,
                                                            hActs[l] ? 1 : 0);
        xin = xc;
    }
    k_pool<<<NG, HID, 0, stream>>>(xc, start, hpool);
    k_fc<<<1, 256, 0, stream>>>(hpool, fcW1, fcb1, fcW, fcb, hout);
}

extern "C" void kernel_launch(void* const* d_in, const int* in_sizes, int n_in,
                              void* d_out, int out_size, void* d_ws, size_t ws_size,
                              hipStream_t stream) {
    const float* x1  = (const float*)d_in[0];
    const int*   ei1 = (const int*)d_in[1];
    const float* ea1 = (const float*)d_in[2];
    const int*   b1  = (const int*)d_in[3];
    const float* x2  = (const float*)d_in[4];
    const int*   ei2 = (const int*)d_in[5];
    const float* ea2 = (const float*)d_in[6];
    const int*   b2  = (const int*)d_in[7];
    const float* convW = (const float*)d_in[8];
    const float* convB = (const float*)d_in[9];
    const float* fcW1  = (const float*)d_in[10];
    const float* fcb1  = (const float*)d_in[11];
    const float* fcW   = (const float*)d_in[12];
    const float* fcb   = (const float*)d_in[13];
    float* out = (float*)d_out;

    // workspace layout (4-byte units)
    float* f      = (float*)d_ws;
    float* deg    = f;                          // NN floats (becomes dinv)
    float* csr_w  = deg + NN;                   // NE floats
    float* xw     = csr_w + NE;                 // NN*HID
    float* xc     = xw + (size_t)NN * HID;      // NN*HID
    float* hpool  = xc + (size_t)NN * HID;      // NG*HID
    float* h1     = hpool + NG * HID;           // NG*OUT
    float* h2     = h1 + NG * OUT;              // NG*OUT
    int*   rowptr = (int*)(h2 + NG * OUT);      // NN+1
    int*   cursor = rowptr + NN + 1;            // NN
    int*   cnt    = cursor + NN;                // NN
    int*   bsum   = cnt + NN;                   // NBLK
    int*   csr_src= bsum + NBLK;                // NE
    int*   start  = csr_src + NE;               // NG+1
    unsigned short* Whi = (unsigned short*)(start + NG + 1);  // 6*16384 bf16
    unsigned short* Wlo = Whi + 6 * 16384;                    // 6*16384 bf16

    // W fragment prep (shared by both towers)
    k_wprep<<<(6 * 16384 + 255) / 256, 256, 0, stream>>>(convW, Whi, Wlo);

    run_tower(x1, ei1, ea1, b1, Whi, Wlo, convB, fcW1, fcb1, fcW, fcb,
              deg, rowptr, cursor, cnt, bsum, csr_src, csr_w, xw, xc,
              hpool, start, h1, stream);
    run_tower(x2, ei2, ea2, b2, Whi, Wlo, convB, fcW1, fcb1, fcW, fcb,
              deg, rowptr, cursor, cnt, bsum, csr_src, csr_w, xw, xc,
              hpool, start, h2, stream);
    k_dist<<<1, NG, 0, stream>>>(h1, h2, out);
}

// Round 13
// 2578.082 us; speedup vs baseline: 14.7410x; 1.1547x over previous
//
#include <hip/hip_runtime.h>
#include <math.h>

// Problem constants (match reference)
constexpr int NN  = 100000;   // nodes
constexpr int NE  = 1600000;  // edges
constexpr int NG  = 64;       // graphs
constexpr int HID = 128;
constexpr int OUT = 64;
constexpr int SCAN_B = 256;
constexpr int NBLK = (NN + SCAN_B - 1) / SCAN_B;  // 391
// ACTS = [True, True, False, True, True, True]
static const bool hActs[6] = {true, true, false, true, true, true};

typedef __attribute__((ext_vector_type(8))) short short8;   // 8 bf16 (4 VGPRs)
typedef __attribute__((ext_vector_type(4))) float f32x4;    // MFMA C/D frag
typedef __attribute__((ext_vector_type(4))) unsigned short us4;  // 4 bf16 (8B)

__device__ __forceinline__ unsigned short f32_to_bf16_rne(float f) {
    unsigned int u = __float_as_uint(f);
    unsigned int r = (u + 0x7fffu + ((u >> 16) & 1u)) >> 16;
    return (unsigned short)r;
}
__device__ __forceinline__ float bf16_to_f32(unsigned short h) {
    return __uint_as_float(((unsigned int)h) << 16);
}

// ---------------- degree / norm precompute ----------------
__global__ void k_deg_init(float* deg) {
    int i = blockIdx.x * 256 + threadIdx.x;
    if (i < NN) deg[i] = 1.0f;  // self-loop weight
}

__global__ void k_deg_acc(const int* __restrict__ dst, const float* __restrict__ ew,
                          float* deg) {
    int e = blockIdx.x * 256 + threadIdx.x;
    if (e < NE) atomicAdd(&deg[dst[e]], ew[e]);
}

__global__ void k_dinv(float* deg) {
    int i = blockIdx.x * 256 + threadIdx.x;
    if (i < NN) {
        float d = deg[i];
        deg[i] = (d > 0.f) ? (1.0f / sqrtf(d)) : 0.0f;
    }
}

// ---------------- W fragment pre-swizzle (once per launch, shared towers) ----
// Fragment-ordered bf16 hi/lo of all 6 conv layers.
// t = ((((l*4 + kc)*8 + ct)*64 + lane)*8 + j
// maps to W[l][kc*32 + (lane>>4)*8 + j][ct*16 + (lane&15)]
__global__ void k_wprep(const float* __restrict__ convW,
                        unsigned short* __restrict__ Whi,
                        unsigned short* __restrict__ Wlo) {
    int t = blockIdx.x * 256 + threadIdx.x;
    if (t >= 6 * 16384) return;
    int j    = t & 7;
    int lane = (t >> 3) & 63;
    int ct   = (t >> 9) & 7;
    int kc   = (t >> 12) & 3;
    int l    = t >> 14;
    int k = kc * 32 + (lane >> 4) * 8 + j;
    int c = ct * 16 + (lane & 15);
    float w = convW[((size_t)l * HID + k) * HID + c];
    unsigned short h = f32_to_bf16_rne(w);
    Whi[t] = h;
    Wlo[t] = f32_to_bf16_rne(w - bf16_to_f32(h));
}

// ---------------- CSR build (once per tower, amortized over 6 layers) ----------
__global__ void k_zero_int(int* __restrict__ p, int n) {
    int i = blockIdx.x * 256 + threadIdx.x;
    if (i < n) p[i] = 0;
}

__global__ void k_count(const int* __restrict__ dst, int* __restrict__ cnt) {
    int e = blockIdx.x * 256 + threadIdx.x;
    if (e < NE) atomicAdd(&cnt[dst[e]], 1);
}

// block-level inclusive scan of cnt -> rowptr[i+1], block sums -> bsum
__global__ __launch_bounds__(SCAN_B) void k_scan_block(const int* __restrict__ cnt,
                                                       int* __restrict__ rowptr,
                                                       int* __restrict__ bsum) {
    __shared__ int s[SCAN_B];
    int i = blockIdx.x * SCAN_B + threadIdx.x;
    int v = (i < NN) ? cnt[i] : 0;
    s[threadIdx.x] = v;
    __syncthreads();
    for (int off = 1; off < SCAN_B; off <<= 1) {
        int x = (threadIdx.x >= off) ? s[threadIdx.x - off] : 0;
        __syncthreads();
        s[threadIdx.x] += x;
        __syncthreads();
    }
    if (i < NN) rowptr[i + 1] = s[threadIdx.x];
    if (threadIdx.x == SCAN_B - 1) bsum[blockIdx.x] = s[threadIdx.x];
}

__global__ void k_scan_partial(int* __restrict__ bsum) {
    if (threadIdx.x == 0) {
        int acc = 0;
        for (int b = 0; b < NBLK; ++b) { int v = bsum[b]; bsum[b] = acc; acc += v; }
    }
}

__global__ void k_scan_add(const int* __restrict__ bsum, int* __restrict__ rowptr) {
    int i = blockIdx.x * SCAN_B + threadIdx.x;
    if (i < NN) rowptr[i + 1] += bsum[blockIdx.x];
    if (i == 0) rowptr[0] = 0;
}

__global__ void k_cursor(const int* __restrict__ rowptr, int* __restrict__ cursor) {
    int i = blockIdx.x * 256 + threadIdx.x;
    if (i < NN) cursor[i] = rowptr[i];
}

// fill CSR: edge weight norm computed inline (f32, matches ref's norm array)
__global__ void k_csr_fill(const int* __restrict__ src, const int* __restrict__ dst,
                           const float* __restrict__ ew, const float* __restrict__ dinv,
                           int* __restrict__ cursor, int* __restrict__ csr_src,
                           float* __restrict__ csr_w) {
    int e = blockIdx.x * 256 + threadIdx.x;
    if (e >= NE) return;
    int s = src[e], d = dst[e];
    float w = dinv[s] * ew[e] * dinv[d];
    int pos = atomicAdd(&cursor[d], 1);
    csr_src[pos] = s;
    csr_w[pos] = w;
}

// Graph start offsets via binary search (batch is sorted)
__global__ void k_bounds(const int* __restrict__ batch, int* __restrict__ start) {
    int g = threadIdx.x;  // 0..NG inclusive
    if (g > NG) return;
    int lo = 0, hi = NN;
    while (lo < hi) {
        int mid = (lo + hi) >> 1;
        if (batch[mid] < g) lo = mid + 1; else hi = mid;
    }
    start[g] = lo;
}

// ---------------- per-layer kernels ----------------
// xw_bf16[N,128] = bf16( x[N,128] @ W[128,128] ) via bf16 split-2 MFMA:
//   x@W ~= xhi@Whi + xlo@Whi + xhi@Wlo  (rel err ~2^-18; output quantized to
//   bf16 to halve the gather's random-read bytes — error budget analysis in
//   round notes: ~5e-10 at output vs 6.6e-9 threshold)
__global__ __launch_bounds__(256) void k_matmul_mfma(const float* __restrict__ x,
                                                     const unsigned short* __restrict__ Whi,
                                                     const unsigned short* __restrict__ Wlo,
                                                     unsigned short* __restrict__ xwb) {
    const int wid  = threadIdx.x >> 6;
    const int lane = threadIdx.x & 63;
    const long rbase = ((long)blockIdx.x * 4 + wid) * 16;
    if (rbase >= NN) return;
    const int arow = lane & 15;
    const int agrp = lane >> 4;

    f32x4 acc[8];
#pragma unroll
    for (int ct = 0; ct < 8; ++ct) acc[ct] = (f32x4){0.f, 0.f, 0.f, 0.f};

    const float* xr = x + (size_t)(rbase + arow) * HID;
#pragma unroll
    for (int kc = 0; kc < 4; ++kc) {
        float4 v0 = *(const float4*)(xr + kc * 32 + agrp * 8);
        float4 v1 = *(const float4*)(xr + kc * 32 + agrp * 8 + 4);
        float vv[8] = {v0.x, v0.y, v0.z, v0.w, v1.x, v1.y, v1.z, v1.w};
        short8 ahi, alo;
#pragma unroll
        for (int j = 0; j < 8; ++j) {
            unsigned short h = f32_to_bf16_rne(vv[j]);
            ahi[j] = (short)h;
            alo[j] = (short)f32_to_bf16_rne(vv[j] - bf16_to_f32(h));
        }
#pragma unroll
        for (int ct = 0; ct < 8; ++ct) {
            short8 bhi = *(const short8*)(Whi + (((size_t)(kc * 8 + ct)) * 64 + lane) * 8);
            short8 blo = *(const short8*)(Wlo + (((size_t)(kc * 8 + ct)) * 64 + lane) * 8);
            acc[ct] = __builtin_amdgcn_mfma_f32_16x16x32_bf16(ahi, bhi, acc[ct], 0, 0, 0);
            acc[ct] = __builtin_amdgcn_mfma_f32_16x16x32_bf16(alo, bhi, acc[ct], 0, 0, 0);
            acc[ct] = __builtin_amdgcn_mfma_f32_16x16x32_bf16(ahi, blo, acc[ct], 0, 0, 0);
        }
    }
    // C store (bf16): row = rbase + agrp*4 + r, col = ct*16 + (lane&15)
#pragma unroll
    for (int ct = 0; ct < 8; ++ct) {
#pragma unroll
        for (int r = 0; r < 4; ++r) {
            xwb[(size_t)(rbase + agrp * 4 + r) * HID + ct * 16 + (lane & 15)] =
                f32_to_bf16_rne(acc[ct][r]);
        }
    }
}

// CSR gather over bf16 xw: xc[n] = act( sum w_e*xw[src_e] + dinv^2*xw[n] + B )
// 32 lanes/node, 4 channels/lane (us4 = 8B loads), double accumulation.
__global__ __launch_bounds__(256) void k_gather(const unsigned short* __restrict__ xwb,
                                                const int* __restrict__ rowptr,
                                                const int* __restrict__ csr_src,
                                                const float* __restrict__ csr_w,
                                                const float* __restrict__ dinv,
                                                const float* __restrict__ B,
                                                float* __restrict__ xc, int act) {
    int t = blockIdx.x * 256 + threadIdx.x;
    int n = t >> 5;
    if (n >= NN) return;
    int q = t & 31;
    const us4* xw4 = (const us4*)xwb;  // row stride: 32 us4 per row
    float d = dinv[n];
    float nself = d * d;
    us4 sv = xw4[(size_t)n * 32 + q];
    double a0 = (double)nself * (double)bf16_to_f32(sv[0]);
    double a1 = (double)nself * (double)bf16_to_f32(sv[1]);
    double a2 = (double)nself * (double)bf16_to_f32(sv[2]);
    double a3 = (double)nself * (double)bf16_to_f32(sv[3]);
    int e1 = rowptr[n + 1];
    for (int e = rowptr[n]; e < e1; ++e) {
        int s = csr_src[e];
        double w = (double)csr_w[e];
        us4 v = xw4[(size_t)s * 32 + q];
        a0 += w * (double)bf16_to_f32(v[0]);
        a1 += w * (double)bf16_to_f32(v[1]);
        a2 += w * (double)bf16_to_f32(v[2]);
        a3 += w * (double)bf16_to_f32(v[3]);
    }
    const float4 b4 = ((const float4*)B)[q];
    float4 o;
    o.x = (float)a0 + b4.x;
    o.y = (float)a1 + b4.y;
    o.z = (float)a2 + b4.z;
    o.w = (float)a3 + b4.w;
    if (act) {
        o.x = tanhf(o.x); o.y = tanhf(o.y); o.z = tanhf(o.z); o.w = tanhf(o.w);
    }
    ((float4*)xc)[(size_t)n * 32 + q] = o;
}

// mean-pool, parallel partials: grid (NG, 8), 128 threads (one per channel).
// Partial sums atomicAdd into hpool (zeroed beforehand); divide happens in k_fc.
__global__ void k_pool_part(const float* __restrict__ x, const int* __restrict__ start,
                            float* __restrict__ h) {
    int g = blockIdx.x;
    int part = blockIdx.y;  // 0..7
    int c = threadIdx.x;    // 128
    int s = start[g], e = start[g + 1];
    int len = e - s;
    int chunk = (len + 7) >> 3;
    int cs = s + part * chunk;
    int ce = cs + chunk < e ? cs + chunk : e;
    if (cs >= ce) return;
    float acc = 0.f;
    for (int n = cs; n < ce; ++n) acc += x[(size_t)n * HID + c];
    atomicAdd(&h[g * HID + c], acc);
}

// whole FC stack in one block (mean divide folded into the load)
__global__ __launch_bounds__(256) void k_fc(const float* __restrict__ hpool,
                                            const int* __restrict__ start,
                                            const float* __restrict__ fcW1,
                                            const float* __restrict__ fcb1,
                                            const float* __restrict__ fcW,
                                            const float* __restrict__ fcb,
                                            float* __restrict__ hout) {
    __shared__ float ha[NG * HID];  // 32KB
    __shared__ float hb[NG * OUT];  // 16KB
    for (int i = threadIdx.x; i < NG * HID; i += 256) {
        int g = i >> 7;
        float cnt = (float)(start[g + 1] - start[g]);
        ha[i] = hpool[i] / fmaxf(cnt, 1.0f);
    }
    __syncthreads();
    // FC1: [64,128] @ [128,64] + b, relu
    for (int idx = threadIdx.x; idx < NG * OUT; idx += 256) {
        int g = idx >> 6, o = idx & 63;
        float acc = fcb1[o];
        for (int k = 0; k < HID; ++k) acc += ha[g * HID + k] * fcW1[k * OUT + o];
        hb[idx] = fmaxf(acc, 0.f);
    }
    __syncthreads();
    // 5 x [64,64] @ [64,64] + b, relu; ping-pong hb -> ha -> hb ...
    for (int l = 0; l < 5; ++l) {
        const float* in = (l & 1) ? ha : hb;
        float* outb     = (l & 1) ? hb : ha;
        const float* W = fcW + l * OUT * OUT;
        const float* b = fcb + l * OUT;
        for (int idx = threadIdx.x; idx < NG * OUT; idx += 256) {
            int g = idx >> 6, o = idx & 63;
            float acc = b[o];
            for (int k = 0; k < OUT; ++k) acc += in[g * OUT + k] * W[k * OUT + o];
            outb[idx] = fmaxf(acc, 0.f);
        }
        __syncthreads();
    }
    for (int idx = threadIdx.x; idx < NG * OUT; idx += 256) hout[idx] = ha[idx];
}

__global__ void k_dist(const float* __restrict__ h1, const float* __restrict__ h2,
                       float* __restrict__ out) {
    int g = threadIdx.x;  // 64
    if (g >= NG) return;
    float acc = 0.f;
    for (int c = 0; c < OUT; ++c) {
        float d = h1[g * OUT + c] - h2[g * OUT + c];
        acc += d * d;
    }
    out[g] = sqrtf(acc);
}

// ---------------- host-side tower driver ----------------
static void run_tower(const float* x_in, const int* ei, const float* ea, const int* batch,
                      const unsigned short* Whi, const unsigned short* Wlo,
                      const float* convB,
                      const float* fcW1, const float* fcb1,
                      const float* fcW, const float* fcb,
                      float* deg, int* rowptr, int* cursor, int* cnt, int* bsum,
                      int* csr_src, float* csr_w, unsigned short* xwb, float* xc,
                      float* hpool, int* start, float* hout, hipStream_t stream) {
    const int* src = ei;
    const int* dst = ei + NE;
    const int gE = (NE + 255) / 256;
    const int gN = (NN + 255) / 256;
    // degree + dinv
    k_deg_init<<<gN, 256, 0, stream>>>(deg);
    k_deg_acc<<<gE, 256, 0, stream>>>(dst, ea, deg);
    k_dinv<<<gN, 256, 0, stream>>>(deg);
    // CSR build
    k_zero_int<<<gN, 256, 0, stream>>>(cnt, NN);
    k_count<<<gE, 256, 0, stream>>>(dst, cnt);
    k_scan_block<<<NBLK, SCAN_B, 0, stream>>>(cnt, rowptr, bsum);
    k_scan_partial<<<1, 64, 0, stream>>>(bsum);
    k_scan_add<<<NBLK, SCAN_B, 0, stream>>>(bsum, rowptr);
    k_cursor<<<gN, 256, 0, stream>>>(rowptr, cursor);
    k_csr_fill<<<gE, 256, 0, stream>>>(src, dst, ea, deg, cursor, csr_src, csr_w);
    k_bounds<<<1, NG + 1, 0, stream>>>(batch, start);

    const int gMM = (NN / 16 + 3) / 4;  // 4 wave-tiles (16 rows each) per block
    const float* xin = x_in;
    for (int l = 0; l < 6; ++l) {
        k_matmul_mfma<<<gMM, 256, 0, stream>>>(xin, Whi + l * 16384, Wlo + l * 16384, xwb);
        k_gather<<<(NN * 32 + 255) / 256, 256, 0, stream>>>(xwb, rowptr, csr_src, csr_w,
                                                            deg, convB + l * HID, xc,
                                                            hActs[l] ? 1 : 0);
        xin = xc;
    }
    k_zero_int<<<(NG * HID + 255) / 256, 256, 0, stream>>>((int*)hpool, NG * HID);
    k_pool_part<<<dim3(NG, 8), HID, 0, stream>>>(xc, start, hpool);
    k_fc<<<1, 256, 0, stream>>>(hpool, start, fcW1, fcb1, fcW, fcb, hout);
}

extern "C" void kernel_launch(void* const* d_in, const int* in_sizes, int n_in,
                              void* d_out, int out_size, void* d_ws, size_t ws_size,
                              hipStream_t stream) {
    const float* x1  = (const float*)d_in[0];
    const int*   ei1 = (const int*)d_in[1];
    const float* ea1 = (const float*)d_in[2];
    const int*   b1  = (const int*)d_in[3];
    const float* x2  = (const float*)d_in[4];
    const int*   ei2 = (const int*)d_in[5];
    const float* ea2 = (const float*)d_in[6];
    const int*   b2  = (const int*)d_in[7];
    const float* convW = (const float*)d_in[8];
    const float* convB = (const float*)d_in[9];
    const float* fcW1  = (const float*)d_in[10];
    const float* fcb1  = (const float*)d_in[11];
    const float* fcW   = (const float*)d_in[12];
    const float* fcb   = (const float*)d_in[13];
    float* out = (float*)d_out;

    // workspace layout (4-byte units; xw region reused as bf16)
    float* f      = (float*)d_ws;
    float* deg    = f;                          // NN floats (becomes dinv)
    float* csr_w  = deg + NN;                   // NE floats
    float* xwf    = csr_w + NE;                 // NN*HID region (bf16 uses half)
    float* xc     = xwf + (size_t)NN * HID;     // NN*HID
    float* hpool  = xc + (size_t)NN * HID;      // NG*HID
    float* h1     = hpool + NG * HID;           // NG*OUT
    float* h2     = h1 + NG * OUT;              // NG*OUT
    int*   rowptr = (int*)(h2 + NG * OUT);      // NN+1
    int*   cursor = rowptr + NN + 1;            // NN
    int*   cnt    = cursor + NN;                // NN
    int*   bsum   = cnt + NN;                   // NBLK
    int*   csr_src= bsum + NBLK;                // NE
    int*   start  = csr_src + NE;               // NG+1
    unsigned short* Whi = (unsigned short*)(start + NG + 1);  // 6*16384 bf16
    unsigned short* Wlo = Whi + 6 * 16384;                    // 6*16384 bf16
    unsigned short* xwb = (unsigned short*)xwf;               // NN*HID bf16

    // W fragment prep (shared by both towers)
    k_wprep<<<(6 * 16384 + 255) / 256, 256, 0, stream>>>(convW, Whi, Wlo);

    run_tower(x1, ei1, ea1, b1, Whi, Wlo, convB, fcW1, fcb1, fcW, fcb,
              deg, rowptr, cursor, cnt, bsum, csr_src, csr_w, xwb, xc,
              hpool, start, h1, stream);
    run_tower(x2, ei2, ea2, b2, Whi, Wlo, convB, fcW1, fcb1, fcW, fcb,
              deg, rowptr, cursor, cnt, bsum, csr_src, csr_w, xwb, xc,
              hpool, start, h2, stream);
    k_dist<<<1, NG, 0, stream>>>(h1, h2, out);
}